// Round 13
// baseline (1886.580 us; speedup 1.0000x reference)
//
#include <hip/hip_runtime.h>
#include <cstdint>

#define S_LEN 32768
#define NV 256
#define NH 512
#define NR 256

typedef short bf16x8 __attribute__((ext_vector_type(8)));
typedef float f32x4 __attribute__((ext_vector_type(4)));
typedef unsigned short ushort_t;
typedef ushort_t u16x8 __attribute__((ext_vector_type(8)));

// ---------------- bf16 helpers (bit-level, RTNE) ----------------
__device__ __forceinline__ float b2f(ushort_t u) {
  return __uint_as_float(((uint32_t)u) << 16);
}
__device__ __forceinline__ ushort_t f2b(float f) {
  uint32_t x = __float_as_uint(f);
  uint32_t r = (x + 0x7fffu + ((x >> 16) & 1u)) >> 16;
  return (ushort_t)r;
}

// ---------------- host threefry2x32 (key-chain derivation) ----------------
#define TFR(x0,x1,r) { x0 += x1; x1 = ((x1 << (r)) | (x1 >> (32 - (r)))); x1 ^= x0; }
__host__ __forceinline__ void tf2x32(uint32_t k0, uint32_t k1,
                                     uint32_t x0, uint32_t x1,
                                     uint32_t* o0, uint32_t* o1) {
  uint32_t k2 = k0 ^ k1 ^ 0x1BD11BDAu;
  x0 += k0; x1 += k1;
  TFR(x0,x1,13) TFR(x0,x1,15) TFR(x0,x1,26) TFR(x0,x1,6)
  x0 += k1; x1 += k2 + 1u;
  TFR(x0,x1,17) TFR(x0,x1,29) TFR(x0,x1,16) TFR(x0,x1,24)
  x0 += k2; x1 += k0 + 2u;
  TFR(x0,x1,13) TFR(x0,x1,15) TFR(x0,x1,26) TFR(x0,x1,6)
  x0 += k0; x1 += k1 + 3u;
  TFR(x0,x1,17) TFR(x0,x1,29) TFR(x0,x1,16) TFR(x0,x1,24)
  x0 += k1; x1 += k2 + 4u;
  TFR(x0,x1,13) TFR(x0,x1,15) TFR(x0,x1,26) TFR(x0,x1,6)
  x0 += k2; x1 += k0 + 5u;
  *o0 = x0; *o1 = x1;
}

// ---------------- device RNG: murmur3 full-avalanche counter hash ----------------
__device__ __forceinline__ float fast_uniform(uint32_t k0, uint32_t k1, uint32_t idx) {
  uint32_t h = idx ^ k0;
  h *= 0xCC9E2D51u; h = (h << 15) | (h >> 17); h *= 0x1B873593u;
  h ^= k1;
  h ^= h >> 16; h *= 0x85EBCA6Bu;
  h ^= h >> 13; h *= 0xC2B2AE35u;
  h ^= h >> 16;
  return __uint_as_float((h >> 9) | 0x3f800000u) - 1.0f;
}

__device__ __forceinline__ float wave_reduce(float v) {
#pragma unroll
  for (int o = 32; o > 0; o >>= 1) v += __shfl_down(v, o, 64);
  return v;
}
__device__ __forceinline__ float softplusf(float z) {
  return fmaxf(z, 0.f) + log1pf(expf(-fabsf(z)));
}

// ---------------- epilogue flags ----------------
#define F_SAMP  4    // Bernoulli sample -> C
#define F_H1    8    // sigmoid -> C2
#define F_FE    16   // softplus sum -> fe_acc (acc += -sign*sum)
#define F_MON   32   // monitor sum vs vseqf -> mon_acc
#define F_DOTB  64   // fe_sum += p * bias_elem   (h1 . bh1t, folded into G1)
#define F_DOTS  128  // fe_sum += sample * bias_elem (sample-side dots)

struct GemmArgs {
  const ushort_t* A;   // [M,K]
  const ushort_t* BT;  // [N,K]
  int boff;            // bias_cat column offset
  ushort_t* C;         // sample out [M,N]
  ushort_t* C2;        // sigmoid out (F_H1)
  const float* vseqf;  // f32 v_seq for F_MON
  double* fe_acc;
  double* mon_acc;
  float sign;
  uint32_t rk0, rk1;
  int N, K, nbx;       // nbx = N/128 (x-block guard for paired launches)
};

// ---------------- core GEMM v4: R10 champion config + SW-pipelined dbuf staging -----
// R10 counters (160us/pair, 1.2 TB/s eff, MfmaUtil 6.5, Occ 20): latency-bound on
// the serial per-K-iter chain load->barrier->MFMA->barrier. R11 (smaller tile) and
// R12 (K-concat bias) both regressed — geometry and bias handling stay R10.
// v4: fetch tile k+1 into regs BEFORE computing tile k; commit to the other LDS
// buffer after; ONE barrier/iter. Load latency overlaps MFMA+ds_read. LDS 64KB ->
// 2 blocks/CU (>= measured 1.6). Bias preloaded into acc (R10-proven).
template<int FLAGS>
__device__ __forceinline__ void run_gemm(const GemmArgs& g,
                                         const ushort_t* __restrict__ biasm, int ldb,
                                         ushort_t* __restrict__ Als,   // 2 x 128x64
                                         ushort_t* __restrict__ Bls) { // 2 x 128x64
  const int tid = threadIdx.x;
  const int lane = tid & 63, wave = tid >> 6;
  const int wm = wave >> 1, wn = wave & 1;
  const int q = lane >> 4, l16 = lane & 15;
  const int m0 = blockIdx.y * 128, n0 = blockIdx.x * 128;
  const int N = g.N, K = g.K;

  f32x4 acc[4][4];
#pragma unroll
  for (int mt = 0; mt < 4; mt++)
#pragma unroll
    for (int nt = 0; nt < 4; nt++) {
      const int gn = n0 + wn * 64 + nt * 16 + l16;
      const int gmb = m0 + wm * 64 + mt * 16 + q * 4;
#pragma unroll
      for (int rg = 0; rg < 4; rg++)
        acc[mt][nt][rg] = b2f(biasm[(size_t)(gmb + rg) * ldb + g.boff + gn]);
    }

  // chunk -> (row, lds block, swizzled global block); constant per thread
  uint4 pa[4], pb[4];
  auto fetch = [&](int kk) {
#pragma unroll
    for (int j = 0; j < 4; j++) {
      int c = j * 256 + tid;
      int r = c >> 3, bl = c & 7, bg = bl ^ (r & 7);
      pa[j] = *(const uint4*)&g.A[(size_t)(m0 + r) * K + kk + bg * 8];
      pb[j] = *(const uint4*)&g.BT[(size_t)(n0 + r) * K + kk + bg * 8];
    }
  };
  auto commit = [&](int buf) {
#pragma unroll
    for (int j = 0; j < 4; j++) {
      int c = j * 256 + tid;
      int r = c >> 3, bl = c & 7;
      *(uint4*)&Als[buf * 8192 + r * 64 + bl * 8] = pa[j];
      *(uint4*)&Bls[buf * 8192 + r * 64 + bl * 8] = pb[j];
    }
  };

  fetch(0);
  commit(0);
  int cur = 0;
  for (int kk = 0; kk < K; kk += 64) {
    const bool more = (kk + 64) < K;
    if (more) fetch(kk + 64);       // loads in flight across the MFMA block
    __syncthreads();                // buf[cur] commits visible; prior reads done
#pragma unroll
    for (int c = 0; c < 2; c++) {
      bf16x8 af[4], bf[4];
#pragma unroll
      for (int mt = 0; mt < 4; mt++) {
        int r = wm * 64 + mt * 16 + l16;
        af[mt] = *(const bf16x8*)&Als[cur * 8192 + r * 64 +
                                      (((c * 4 + q) ^ (r & 7)) * 8)];
      }
#pragma unroll
      for (int nt = 0; nt < 4; nt++) {
        int r = wn * 64 + nt * 16 + l16;
        bf[nt] = *(const bf16x8*)&Bls[cur * 8192 + r * 64 +
                                      (((c * 4 + q) ^ (r & 7)) * 8)];
      }
#pragma unroll
      for (int mt = 0; mt < 4; mt++)
#pragma unroll
        for (int nt = 0; nt < 4; nt++)
          acc[mt][nt] = __builtin_amdgcn_mfma_f32_16x16x32_bf16(
              af[mt], bf[nt], acc[mt][nt], 0, 0, 0);
    }
    if (more) { commit(1 - cur); cur ^= 1; }  // no wave reads buf[1-cur] this iter
  }

  float fe_sum = 0.f, mon_sum = 0.f;
#pragma unroll
  for (int mt = 0; mt < 4; mt++) {
#pragma unroll
    for (int nt = 0; nt < 4; nt++) {
      const int gn = n0 + wn * 64 + nt * 16 + l16;
      const int gmb = m0 + wm * 64 + mt * 16 + q * 4;
#pragma unroll
      for (int rg = 0; rg < 4; rg++) {
        const int gm = gmb + rg;
        const size_t idx = (size_t)gm * N + gn;
        float z = acc[mt][nt][rg];  // bias already inside
        float be = 0.f;
        if constexpr (FLAGS & (F_DOTB | F_DOTS))
          be = b2f(biasm[(size_t)gm * ldb + g.boff + gn]);
        if constexpr (FLAGS & (F_SAMP | F_H1 | F_MON)) {
          float e = __expf(-z);
          if constexpr (FLAGS & F_SAMP) {
            float uu = fast_uniform(g.rk0, g.rk1, (uint32_t)idx);
            bool sbit = fmaf(uu, e, uu) < 1.f;  // u < sigmoid(z)
            g.C[idx] = sbit ? (ushort_t)0x3f80 : (ushort_t)0;
            if constexpr (FLAGS & F_DOTS) fe_sum += sbit ? be : 0.f;
          }
          if constexpr (FLAGS & (F_H1 | F_MON)) {
            float pp = __builtin_amdgcn_rcpf(1.f + e);
            if constexpr (FLAGS & F_H1) g.C2[idx] = f2b(pp);
            if constexpr (FLAGS & F_DOTB) fe_sum += pp * be;
            if constexpr (FLAGS & F_MON) {
              float v = g.vseqf[idx];
              mon_sum += (v != 0.f) ? logf(pp + 1e-10f) : logf(1.f - pp + 1e-10f);
            }
          }
        }
        if constexpr (FLAGS & F_FE) fe_sum += softplusf(z);
      }
    }
  }
  if constexpr (FLAGS & (F_FE | F_DOTB | F_DOTS)) {
    float s = wave_reduce(fe_sum);
    if (lane == 0) atomicAdd(g.fe_acc, (double)(-g.sign * s));
  }
  if constexpr (FLAGS & F_MON) {
    float s = wave_reduce(mon_sum);
    if (lane == 0) atomicAdd(g.mon_acc, (double)s);
  }
}

template<int FLAGS>
__global__ __launch_bounds__(256)
void gemm_samp(GemmArgs g, const ushort_t* __restrict__ biasm, int ldb) {
  __shared__ ushort_t Als[2 * 128 * 64];
  __shared__ ushort_t Bls[2 * 128 * 64];
  if ((int)blockIdx.x >= g.nbx) return;
  run_gemm<FLAGS>(g, biasm, ldb, Als, Bls);
}

// Paired launch: z=0 runs g0 (RBM1 step), z=1 runs g1 (RBM2 step) — independent.
template<int F0, int F1>
__global__ __launch_bounds__(256)
void gemm_pair(GemmArgs g0, GemmArgs g1, const ushort_t* __restrict__ biasm, int ldb) {
  __shared__ ushort_t Als[2 * 128 * 64];
  __shared__ ushort_t Bls[2 * 128 * 64];
  if (blockIdx.z == 0) {
    if ((int)blockIdx.x >= g0.nbx) return;
    run_gemm<F0>(g0, biasm, ldb, Als, Bls);
  } else {
    if ((int)blockIdx.x >= g1.nbx) return;
    run_gemm<F1>(g1, biasm, ldb, Als, Bls);
  }
}

// ---------------- plain GEMM + f32-vector bias (Arnn / bias_cat; not hot) -----------
// VDOT (bias_cat GEMM only): for n0<256 accumulate z * v_seq[gm,gn] -> acc += -sum
template<bool OUTF32, bool VDOT>
__global__ __launch_bounds__(256)
void gemm_bias(const ushort_t* __restrict__ A, const ushort_t* __restrict__ BT,
               const float* __restrict__ biasv, ushort_t* __restrict__ Cb,
               float* __restrict__ Cf, const float* __restrict__ vdata,
               double* __restrict__ dacc, int M, int N, int K) {
  __shared__ ushort_t Als[128 * 64];
  __shared__ ushort_t Bls[128 * 64];
  const int tid = threadIdx.x;
  const int lane = tid & 63, wave = tid >> 6;
  const int wm = wave >> 1, wn = wave & 1;
  const int q = lane >> 4, l16 = lane & 15;
  const int m0 = blockIdx.y * 128, n0 = blockIdx.x * 128;

  f32x4 acc[4][4];
#pragma unroll
  for (int i = 0; i < 4; i++)
#pragma unroll
    for (int j = 0; j < 4; j++) acc[i][j] = (f32x4){0.f, 0.f, 0.f, 0.f};

  for (int kk = 0; kk < K; kk += 64) {
#pragma unroll
    for (int j = 0; j < 4; j++) {
      int c = j * 256 + tid;
      int r = c >> 3, bl = c & 7, bg = bl ^ (r & 7);
      *(uint4*)&Als[r * 64 + bl * 8] =
          *(const uint4*)&A[(size_t)(m0 + r) * K + kk + bg * 8];
      *(uint4*)&Bls[r * 64 + bl * 8] =
          *(const uint4*)&BT[(size_t)(n0 + r) * K + kk + bg * 8];
    }
    __syncthreads();
#pragma unroll
    for (int c = 0; c < 2; c++) {
      bf16x8 af[4], bf[4];
#pragma unroll
      for (int mt = 0; mt < 4; mt++) {
        int r = wm * 64 + mt * 16 + l16;
        af[mt] = *(const bf16x8*)&Als[r * 64 + (((c * 4 + q) ^ (r & 7)) * 8)];
      }
#pragma unroll
      for (int nt = 0; nt < 4; nt++) {
        int r = wn * 64 + nt * 16 + l16;
        bf[nt] = *(const bf16x8*)&Bls[r * 64 + (((c * 4 + q) ^ (r & 7)) * 8)];
      }
#pragma unroll
      for (int mt = 0; mt < 4; mt++)
#pragma unroll
        for (int nt = 0; nt < 4; nt++)
          acc[mt][nt] = __builtin_amdgcn_mfma_f32_16x16x32_bf16(
              af[mt], bf[nt], acc[mt][nt], 0, 0, 0);
    }
    __syncthreads();
  }
  float dsum = 0.f;
#pragma unroll
  for (int mt = 0; mt < 4; mt++)
#pragma unroll
    for (int nt = 0; nt < 4; nt++) {
      const int gn = n0 + wn * 64 + nt * 16 + l16;
      const int gmb = m0 + wm * 64 + mt * 16 + q * 4;
      const float bvv = biasv[gn];
#pragma unroll
      for (int rg = 0; rg < 4; rg++) {
        const size_t idx = (size_t)(gmb + rg) * N + gn;
        float z = acc[mt][nt][rg] + bvv;
        if constexpr (OUTF32) Cf[idx] = z; else Cb[idx] = f2b(z);
        if constexpr (VDOT)
          if (n0 < 256) dsum += z * vdata[(size_t)(gmb + rg) * 256 + gn];
      }
    }
  if constexpr (VDOT) {
    if (n0 < 256) {
      float s = wave_reduce(dsum);
      if ((tid & 63) == 0) atomicAdd(dacc, (double)(-s));  // cost1 -= v.bv_t
    }
  }
}

// ---------------- chunked RNN scan v5 (R10-proven) ----------------
__global__ __launch_bounds__(1024, 1)
void rnn_scan(const float* __restrict__ Apre, const float* __restrict__ Wuu,
              ushort_t* __restrict__ shifted) {
  const int tid = threadIdx.x;
  const int j = tid >> 2;
  const int s = tid & 3;
  const int t_begin = blockIdx.x * 128;
  const int t_end = t_begin + 128;
  const int t0 = (t_begin >= 16) ? (t_begin - 16) : 0;

  float w[64];
#pragma unroll
  for (int i = 0; i < 64; i++) w[i] = Wuu[(size_t)(s * 64 + i) * 256 + j];

  __shared__ float u[2][280];
  __shared__ float asg[32 * 256];
  if (tid < 256) u[0][(tid >> 6) * 68 + (tid & 63)] = 0.f;
  if (blockIdx.x == 0 && s == 0) shifted[j] = 0;
  __syncthreads();

  const int jp = (j >> 6) * 68 + (j & 63);
  int p = 0;
  for (int tb = t0; tb < t_end; tb += 32) {
    int srow = tb + (tid >> 5);
    if (srow >= S_LEN) srow = S_LEN - 1;
    int scol = (tid & 31) * 8;
    float4 a0 = *(const float4*)&Apre[(size_t)srow * 256 + scol];
    float4 a1 = *(const float4*)&Apre[(size_t)srow * 256 + scol + 4];
    *(float4*)&asg[(tid >> 5) * 256 + scol] = a0;
    *(float4*)&asg[(tid >> 5) * 256 + scol + 4] = a1;
    __syncthreads();
#pragma unroll 1
    for (int i = 0; i < 32; i++) {
      const int t = tb + i;
      if (t >= t_end) break;
      float p0 = 0.f, p1 = 0.f, p2 = 0.f, p3 = 0.f;
#pragma unroll
      for (int qq = 0; qq < 64; qq += 4) {
        float4 uv = *(const float4*)&u[p][s * 68 + qq];
        p0 = fmaf(uv.x, w[qq + 0], p0);
        p1 = fmaf(uv.y, w[qq + 1], p1);
        p2 = fmaf(uv.z, w[qq + 2], p2);
        p3 = fmaf(uv.w, w[qq + 3], p3);
      }
      float ps = (p0 + p1) + (p2 + p3);
      ps += __shfl_xor(ps, 1, 64);
      ps += __shfl_xor(ps, 2, 64);
      float z = asg[i * 256 + j] + ps;
      float e = __expf(2.f * z);
      float unew = 1.f - 2.f * __builtin_amdgcn_rcpf(e + 1.f);
      if (s == 0) {
        u[1 - p][jp] = unew;
        if (t >= t_begin && (t + 1) < S_LEN)
          shifted[(size_t)(t + 1) * 256 + j] = f2b(unew);
      }
      __syncthreads();
      p ^= 1;
    }
  }
}

// ---------------- single prep kernel ----------------
__global__ __launch_bounds__(256)
void prep_all(const float* __restrict__ v_seq, ushort_t* __restrict__ vseq_bf,
              const float* __restrict__ Wyv, const float* __restrict__ Wyh1,
              const float* __restrict__ Wyh2, ushort_t* __restrict__ Wycat,
              const float* __restrict__ W1, ushort_t* __restrict__ BTw1t,
              ushort_t* __restrict__ BTw1,
              const float* __restrict__ W2, ushort_t* __restrict__ BTw2t,
              ushort_t* __restrict__ BTw2,
              const float* __restrict__ Wvu, ushort_t* __restrict__ BTwvu,
              const float* __restrict__ bv, const float* __restrict__ bh1,
              const float* __restrict__ bh2, float* __restrict__ bveccat) {
  int b = blockIdx.x;
  const int tid = threadIdx.x;
  if (b < 32768) { int i = b * 256 + tid; vseq_bf[i] = f2b(v_seq[i]); return; }
  b -= 32768;
  if (b < 256)  { int i = b * 256 + tid; Wycat[i] = f2b(Wyv[i]); return; }
  b -= 256;
  if (b < 512)  { int i = b * 256 + tid; Wycat[65536 + i] = f2b(Wyh1[i]); return; }
  b -= 512;
  if (b < 512)  { int i = b * 256 + tid; Wycat[196608 + i] = f2b(Wyh2[i]); return; }
  b -= 512;
  if (b < 512)  { int i = b * 256 + tid; BTw1t[i] = f2b(W1[i]); return; }
  b -= 512;
  if (b < 1024) { int i = b * 256 + tid; BTw2t[i] = f2b(W2[i]); return; }
  b -= 1024;
  if (b < 256)  { int i = b * 256 + tid; int r = i >> 8, c = i & 255;
                  BTwvu[c * 256 + r] = f2b(Wvu[i]); return; }
  b -= 256;
  if (b < 512)  { int i = b * 256 + tid; int r = i >> 9, c = i & 511;
                  BTw1[(size_t)c * 256 + r] = f2b(W1[i]); return; }
  b -= 512;
  if (b < 1024) { int i = b * 256 + tid; int r = i >> 9, c = i & 511;
                  BTw2[(size_t)c * 512 + r] = f2b(W2[i]); return; }
  b -= 1024;
  { int i = b * 256 + tid;
    if (i < 1280)
      bveccat[i] = (i < 256) ? bv[i] : (i < 768) ? bh1[i - 256] : bh2[i - 768]; }
}

__global__ void finalize_kernel(const double* __restrict__ acc, float* __restrict__ out) {
  out[0] = (float)(acc[0] / (double)S_LEN);
  out[1] = (float)(acc[1] / (double)S_LEN);
}

// ---------------- host orchestration ----------------
extern "C" void kernel_launch(void* const* d_in, const int* in_sizes, int n_in,
                              void* d_out, int out_size, void* d_ws, size_t ws_size,
                              hipStream_t stream) {
  (void)in_sizes; (void)n_in; (void)out_size; (void)ws_size;
  const float* v_seq = (const float*)d_in[0];
  const float* W1    = (const float*)d_in[1];
  const float* bv    = (const float*)d_in[2];
  const float* bh1   = (const float*)d_in[3];
  const float* W2    = (const float*)d_in[4];
  const float* bh2   = (const float*)d_in[5];
  const float* Wyv   = (const float*)d_in[6];
  const float* Wyh1  = (const float*)d_in[7];
  const float* Wyh2  = (const float*)d_in[8];
  const float* Wvu   = (const float*)d_in[9];
  const float* Wuu   = (const float*)d_in[10];
  const float* bu    = (const float*)d_in[11];
  float* out = (float*)d_out;

  const size_t SN = (size_t)S_LEN * NV;   // 8.4M
  const size_t SH = (size_t)S_LEN * NH;   // 16.8M
  const int NB = NV + NH + NH;            // 1280
  char* base = (char*)d_ws;
  size_t cur = 0;
  auto take = [&](size_t bytes) { size_t o = cur; cur += (bytes + 255) & ~(size_t)255; return o; };
  double*   acc      = (double*)  (base + take(64));
  ushort_t* BTwvu    = (ushort_t*)(base + take(65536 * 2));
  ushort_t* Wycat    = (ushort_t*)(base + take((size_t)NB * NR * 2));
  float*    bveccat  = (float*)   (base + take(NB * 4));
  ushort_t* BTw1     = (ushort_t*)(base + take(131072 * 2));   // W1^T [512,256]
  ushort_t* BTw1t    = (ushort_t*)(base + take(131072 * 2));   // W1   [256,512]
  ushort_t* BTw2     = (ushort_t*)(base + take(262144 * 2));   // W2^T [512,512]
  ushort_t* BTw2t    = (ushort_t*)(base + take(262144 * 2));   // W2   [512,512]
  ushort_t* vseq_bf  = (ushort_t*)(base + take(SN * 2));       // + shifted = sampC span
  ushort_t* shifted  = (ushort_t*)(base + take(SN * 2));
  ushort_t* bias_cat = (ushort_t*)(base + take((size_t)S_LEN * NB * 2)); // [S,1280]
  ushort_t* h1buf    = (ushort_t*)(base + take(SH * 2));       // aliased by sampD late
  ushort_t* sampA    = (ushort_t*)(base + take(SH * 2));       // RBM1 h samples
  ushort_t* sampB    = (ushort_t*)(base + take(SN * 2));       // RBM1 v samples
  // Aliases (lifetime-checked):
  float*    Arnn  = (float*)bias_cat;  // consumed by rnn before bias GEMM
  ushort_t* sampC = vseq_bf;           // [S,512] over vseq_bf+shifted; dead after G1
  ushort_t* sampD = h1buf;             // h1buf dead after A0 (dot folded into G1)

  uint32_t ka[20], kb[20];
  uint32_t K0 = 0u, K1 = 42u;
  for (int it = 0; it < 10; it++) {
    uint32_t n0, n1, a0, a1, b0, b1;
    tf2x32(K0, K1, 0u, 0u, &n0, &n1);
    tf2x32(K0, K1, 0u, 1u, &a0, &a1);
    tf2x32(K0, K1, 0u, 2u, &b0, &b1);
    ka[2 * it] = a0; kb[2 * it] = a1;
    ka[2 * it + 1] = b0; kb[2 * it + 1] = b1;
    K0 = n0; K1 = n1;
  }

  hipMemsetAsync(acc, 0, 2 * sizeof(double), stream);

  dim3 blk(256);
  prep_all<<<dim3(37381), blk, 0, stream>>>(
      v_seq, vseq_bf, Wyv, Wyh1, Wyh2, Wycat, W1, BTw1t, BTw1,
      W2, BTw2t, BTw2, Wvu, BTwvu, bv, bh1, bh2, bveccat);

  const int M = S_LEN;
  gemm_bias<true, false><<<dim3(2, M / 128), blk, 0, stream>>>(
      vseq_bf, BTwvu, bu, nullptr, Arnn, nullptr, nullptr, M, NV, NV);
  rnn_scan<<<dim3(S_LEN / 128), dim3(1024), 0, stream>>>(Arnn, Wuu, shifted);
  gemm_bias<false, true><<<dim3(NB / 128, M / 128), blk, 0, stream>>>(
      shifted, Wycat, bveccat, bias_cat, nullptr, v_seq, acc, M, NB, NR);

  const int OFF_BV = 0, OFF_BH1 = NV, OFF_BH2 = NV + NH;
  auto mk = [&](const ushort_t* A, const ushort_t* BT, int boff, ushort_t* C,
                ushort_t* C2, const float* vs, float sign, int key, int N, int K) {
    GemmArgs g;
    g.A = A; g.BT = BT; g.boff = boff; g.C = C; g.C2 = C2; g.vseqf = vs;
    g.fe_acc = acc; g.mon_acc = acc + 1; g.sign = sign;
    g.rk0 = key >= 0 ? ka[key] : 0; g.rk1 = key >= 0 ? kb[key] : 0;
    g.N = N; g.K = K; g.nbx = N / 128;
    return g;
  };

  // G1: sample h (sampA), h1 (h1buf), cost1 -= softplus(z), cost2 -= h1.bh1t
  gemm_samp<F_SAMP | F_H1 | F_FE | F_DOTB><<<dim3(4, M / 128), blk, 0, stream>>>(
      mk(vseq_bf, BTw1, OFF_BH1, sampA, h1buf, nullptr, 1.0f, 0, NH, NV),
      bias_cat, NB);

  // 10 paired dispatches: RBM1 chain (z=0) + RBM2 chain (z=1)
  dim3 pg(4, M / 128, 2);
  GemmArgs V[5], Hh[4], A2g[5], B2g[5];
  for (int it = 0; it < 5; it++) {
    if (it > 0)
      Hh[it - 1] = mk(sampB, BTw1, OFF_BH1, sampA, nullptr, nullptr, 0.f,
                      2 * it, NH, NV);
    V[it] = mk(sampA, BTw1t, OFF_BV, sampB, nullptr,
               (it == 4) ? v_seq : nullptr, (it == 4) ? -1.0f : 0.f,
               2 * it + 1, NV, NH);
    A2g[it] = mk((it == 0) ? h1buf : sampD, BTw2, OFF_BH2, sampC, nullptr, nullptr,
                 (it == 0) ? 1.0f : 0.f, 10 + 2 * it, NH, NH);
    B2g[it] = mk(sampC, BTw2t, OFF_BH1, sampD, nullptr, nullptr,
                 (it == 4) ? -1.0f : 0.f, 11 + 2 * it, NH, NH);
  }
  GemmArgs FE1 = mk(sampB, BTw1, OFF_BH1, nullptr, nullptr, nullptr, -1.0f,
                    -1, NH, NV);
  GemmArgs FE2 = mk(sampD, BTw2, OFF_BH2, nullptr, nullptr, nullptr, -1.0f,
                    -1, NH, NH);

  gemm_pair<F_SAMP, F_SAMP | F_FE><<<pg, blk, 0, stream>>>(V[0], A2g[0], bias_cat, NB);
  gemm_pair<F_SAMP, F_SAMP><<<pg, blk, 0, stream>>>(Hh[0], B2g[0], bias_cat, NB);
  gemm_pair<F_SAMP, F_SAMP><<<pg, blk, 0, stream>>>(V[1], A2g[1], bias_cat, NB);
  gemm_pair<F_SAMP, F_SAMP><<<pg, blk, 0, stream>>>(Hh[1], B2g[1], bias_cat, NB);
  gemm_pair<F_SAMP, F_SAMP><<<pg, blk, 0, stream>>>(V[2], A2g[2], bias_cat, NB);
  gemm_pair<F_SAMP, F_SAMP><<<pg, blk, 0, stream>>>(Hh[2], B2g[2], bias_cat, NB);
  gemm_pair<F_SAMP, F_SAMP><<<pg, blk, 0, stream>>>(V[3], A2g[3], bias_cat, NB);
  gemm_pair<F_SAMP, F_SAMP><<<pg, blk, 0, stream>>>(Hh[3], B2g[3], bias_cat, NB);
  gemm_pair<F_SAMP | F_MON | F_DOTS, F_SAMP><<<pg, blk, 0, stream>>>(
      V[4], A2g[4], bias_cat, NB);
  gemm_pair<F_FE, F_SAMP | F_DOTS><<<pg, blk, 0, stream>>>(FE1, B2g[4], bias_cat, NB);

  // FE2(sample): cost2 += softplus(h1s@W2 + bh2t)
  gemm_samp<F_FE><<<dim3(4, M / 128), blk, 0, stream>>>(FE2, bias_cat, NB);

  finalize_kernel<<<1, 1, 0, stream>>>(acc, out);
}

// Round 14
// 1846.781 us; speedup vs baseline: 1.0216x; 1.0216x over previous
//
#include <hip/hip_runtime.h>
#include <cstdint>

#define S_LEN 32768
#define NV 256
#define NH 512
#define NR 256

typedef short bf16x8 __attribute__((ext_vector_type(8)));
typedef float f32x4 __attribute__((ext_vector_type(4)));
typedef unsigned short ushort_t;
typedef ushort_t u16x8 __attribute__((ext_vector_type(8)));

// ---------------- bf16 helpers (bit-level, RTNE) ----------------
__device__ __forceinline__ float b2f(ushort_t u) {
  return __uint_as_float(((uint32_t)u) << 16);
}
__device__ __forceinline__ ushort_t f2b(float f) {
  uint32_t x = __float_as_uint(f);
  uint32_t r = (x + 0x7fffu + ((x >> 16) & 1u)) >> 16;
  return (ushort_t)r;
}

// ---------------- host threefry2x32 (key-chain derivation) ----------------
#define TFR(x0,x1,r) { x0 += x1; x1 = ((x1 << (r)) | (x1 >> (32 - (r)))); x1 ^= x0; }
__host__ __forceinline__ void tf2x32(uint32_t k0, uint32_t k1,
                                     uint32_t x0, uint32_t x1,
                                     uint32_t* o0, uint32_t* o1) {
  uint32_t k2 = k0 ^ k1 ^ 0x1BD11BDAu;
  x0 += k0; x1 += k1;
  TFR(x0,x1,13) TFR(x0,x1,15) TFR(x0,x1,26) TFR(x0,x1,6)
  x0 += k1; x1 += k2 + 1u;
  TFR(x0,x1,17) TFR(x0,x1,29) TFR(x0,x1,16) TFR(x0,x1,24)
  x0 += k2; x1 += k0 + 2u;
  TFR(x0,x1,13) TFR(x0,x1,15) TFR(x0,x1,26) TFR(x0,x1,6)
  x0 += k0; x1 += k1 + 3u;
  TFR(x0,x1,17) TFR(x0,x1,29) TFR(x0,x1,16) TFR(x0,x1,24)
  x0 += k1; x1 += k2 + 4u;
  TFR(x0,x1,13) TFR(x0,x1,15) TFR(x0,x1,26) TFR(x0,x1,6)
  x0 += k2; x1 += k0 + 5u;
  *o0 = x0; *o1 = x1;
}

// ---------------- device RNG: murmur3 full-avalanche counter hash ----------------
__device__ __forceinline__ float fast_uniform(uint32_t k0, uint32_t k1, uint32_t idx) {
  uint32_t h = idx ^ k0;
  h *= 0xCC9E2D51u; h = (h << 15) | (h >> 17); h *= 0x1B873593u;
  h ^= k1;
  h ^= h >> 16; h *= 0x85EBCA6Bu;
  h ^= h >> 13; h *= 0xC2B2AE35u;
  h ^= h >> 16;
  return __uint_as_float((h >> 9) | 0x3f800000u) - 1.0f;
}

__device__ __forceinline__ float wave_reduce(float v) {
#pragma unroll
  for (int o = 32; o > 0; o >>= 1) v += __shfl_down(v, o, 64);
  return v;
}
__device__ __forceinline__ float softplusf(float z) {
  return fmaxf(z, 0.f) + log1pf(expf(-fabsf(z)));
}

// ---------------- epilogue flags ----------------
#define F_SAMP  4    // Bernoulli sample -> C
#define F_H1    8    // sigmoid -> C2
#define F_FE    16   // softplus sum -> fe_acc (acc += -sign*sum)
#define F_MON   32   // monitor sum vs vseqf -> mon_acc
#define F_DOTB  64   // fe_sum += p * bias_elem   (h1 . bh1t, folded into G1)
#define F_DOTS  128  // fe_sum += sample * bias_elem (sample-side dots)

struct GemmArgs {
  const ushort_t* A;   // [M,K]
  const ushort_t* BT;  // [N,K]
  int boff;            // bias_cat column offset
  ushort_t* C;         // sample out [M,N]
  ushort_t* C2;        // sigmoid out (F_H1)
  const float* vseqf;  // f32 v_seq for F_MON
  double* fe_acc;
  double* mon_acc;
  float sign;
  uint32_t rk0, rk1;
  int N, K, nbx;       // nbx = N/128 (x-block guard for paired launches)
};

// ---------------- core GEMM body — R10 CHAMPION CONFIG (restored verbatim) ----------
// The R10 config (128x128 tile, uint4 staging, XOR swizzle, bias preloaded into acc,
// v1 scalar epilogue, murmur RNG) measured 1435us total. All counter-motivated
// perturbations regressed and were reverted:
//   R11 128x64 tile + XCD swizzle: 1549 (A-staging doubled; FETCH unchanged)
//   R12 K-concat dynamic bias:     1519 (shifted re-staged per block: FETCH 149->183MB)
//   R13 SW-pipelined LDS dbuf:     1886 (reg prefetch spilled: WRITE 33->150MB;
//                                        write/read phase mixing: conflicts 0->4.5e6)
//   R6-8 persistent LDS chains:    1972+ (latency-bound at 8 waves/CU; packed
//                                        weights thrashed L2: FETCH 233MB->2.6GB)
// This is a bracketed local optimum of the launched-GEMM decomposition.
template<int FLAGS>
__device__ __forceinline__ void run_gemm(const GemmArgs& g,
                                         const ushort_t* __restrict__ biasm, int ldb,
                                         ushort_t* __restrict__ Als,
                                         ushort_t* __restrict__ Bls) {
  const int tid = threadIdx.x;
  const int lane = tid & 63, wave = tid >> 6;
  const int wm = wave >> 1, wn = wave & 1;
  const int q = lane >> 4, l16 = lane & 15;
  const int m0 = blockIdx.y * 128, n0 = blockIdx.x * 128;
  const int N = g.N, K = g.K;

  f32x4 acc[4][4];
#pragma unroll
  for (int mt = 0; mt < 4; mt++)
#pragma unroll
    for (int nt = 0; nt < 4; nt++) {
      const int gn = n0 + wn * 64 + nt * 16 + l16;
      const int gmb = m0 + wm * 64 + mt * 16 + q * 4;
#pragma unroll
      for (int rg = 0; rg < 4; rg++)
        acc[mt][nt][rg] = b2f(biasm[(size_t)(gmb + rg) * ldb + g.boff + gn]);
    }

  for (int kk = 0; kk < K; kk += 64) {
#pragma unroll
    for (int j = 0; j < 4; j++) {
      int c = j * 256 + tid;
      int r = c >> 3, bl = c & 7, bg = bl ^ (r & 7);
      *(uint4*)&Als[r * 64 + bl * 8] =
          *(const uint4*)&g.A[(size_t)(m0 + r) * K + kk + bg * 8];
      *(uint4*)&Bls[r * 64 + bl * 8] =
          *(const uint4*)&g.BT[(size_t)(n0 + r) * K + kk + bg * 8];
    }
    __syncthreads();
#pragma unroll
    for (int c = 0; c < 2; c++) {
      bf16x8 af[4], bf[4];
#pragma unroll
      for (int mt = 0; mt < 4; mt++) {
        int r = wm * 64 + mt * 16 + l16;
        af[mt] = *(const bf16x8*)&Als[r * 64 + (((c * 4 + q) ^ (r & 7)) * 8)];
      }
#pragma unroll
      for (int nt = 0; nt < 4; nt++) {
        int r = wn * 64 + nt * 16 + l16;
        bf[nt] = *(const bf16x8*)&Bls[r * 64 + (((c * 4 + q) ^ (r & 7)) * 8)];
      }
#pragma unroll
      for (int mt = 0; mt < 4; mt++)
#pragma unroll
        for (int nt = 0; nt < 4; nt++)
          acc[mt][nt] = __builtin_amdgcn_mfma_f32_16x16x32_bf16(
              af[mt], bf[nt], acc[mt][nt], 0, 0, 0);
    }
    __syncthreads();
  }

  float fe_sum = 0.f, mon_sum = 0.f;
#pragma unroll
  for (int mt = 0; mt < 4; mt++) {
#pragma unroll
    for (int nt = 0; nt < 4; nt++) {
      const int gn = n0 + wn * 64 + nt * 16 + l16;
      const int gmb = m0 + wm * 64 + mt * 16 + q * 4;
#pragma unroll
      for (int rg = 0; rg < 4; rg++) {
        const int gm = gmb + rg;
        const size_t idx = (size_t)gm * N + gn;
        float z = acc[mt][nt][rg];  // bias already inside
        float be = 0.f;
        if constexpr (FLAGS & (F_DOTB | F_DOTS))
          be = b2f(biasm[(size_t)gm * ldb + g.boff + gn]);
        if constexpr (FLAGS & (F_SAMP | F_H1 | F_MON)) {
          float e = __expf(-z);
          if constexpr (FLAGS & F_SAMP) {
            float uu = fast_uniform(g.rk0, g.rk1, (uint32_t)idx);
            bool sbit = fmaf(uu, e, uu) < 1.f;  // u < sigmoid(z)
            g.C[idx] = sbit ? (ushort_t)0x3f80 : (ushort_t)0;
            if constexpr (FLAGS & F_DOTS) fe_sum += sbit ? be : 0.f;
          }
          if constexpr (FLAGS & (F_H1 | F_MON)) {
            float pp = __builtin_amdgcn_rcpf(1.f + e);
            if constexpr (FLAGS & F_H1) g.C2[idx] = f2b(pp);
            if constexpr (FLAGS & F_DOTB) fe_sum += pp * be;
            if constexpr (FLAGS & F_MON) {
              float v = g.vseqf[idx];
              mon_sum += (v != 0.f) ? logf(pp + 1e-10f) : logf(1.f - pp + 1e-10f);
            }
          }
        }
        if constexpr (FLAGS & F_FE) fe_sum += softplusf(z);
      }
    }
  }
  if constexpr (FLAGS & (F_FE | F_DOTB | F_DOTS)) {
    float s = wave_reduce(fe_sum);
    if (lane == 0) atomicAdd(g.fe_acc, (double)(-g.sign * s));
  }
  if constexpr (FLAGS & F_MON) {
    float s = wave_reduce(mon_sum);
    if (lane == 0) atomicAdd(g.mon_acc, (double)s);
  }
}

template<int FLAGS>
__global__ __launch_bounds__(256)
void gemm_samp(GemmArgs g, const ushort_t* __restrict__ biasm, int ldb) {
  __shared__ ushort_t Als[128 * 64];
  __shared__ ushort_t Bls[128 * 64];
  if ((int)blockIdx.x >= g.nbx) return;
  run_gemm<FLAGS>(g, biasm, ldb, Als, Bls);
}

// Paired launch: z=0 runs g0 (RBM1 step), z=1 runs g1 (RBM2 step) — the two CD
// chains are independent after G1 (RBM2 needs only h1buf); pairing halves the
// number of serial dispatch rounds (23 -> 12).
template<int F0, int F1>
__global__ __launch_bounds__(256)
void gemm_pair(GemmArgs g0, GemmArgs g1, const ushort_t* __restrict__ biasm, int ldb) {
  __shared__ ushort_t Als[128 * 64];
  __shared__ ushort_t Bls[128 * 64];
  if (blockIdx.z == 0) {
    if ((int)blockIdx.x >= g0.nbx) return;
    run_gemm<F0>(g0, biasm, ldb, Als, Bls);
  } else {
    if ((int)blockIdx.x >= g1.nbx) return;
    run_gemm<F1>(g1, biasm, ldb, Als, Bls);
  }
}

// ---------------- plain GEMM + f32-vector bias (Arnn / bias_cat) --------------------
// VDOT (bias_cat GEMM only): for n0<256 accumulate z * v_seq[gm,gn] -> acc += -sum
template<bool OUTF32, bool VDOT>
__global__ __launch_bounds__(256)
void gemm_bias(const ushort_t* __restrict__ A, const ushort_t* __restrict__ BT,
               const float* __restrict__ biasv, ushort_t* __restrict__ Cb,
               float* __restrict__ Cf, const float* __restrict__ vdata,
               double* __restrict__ dacc, int M, int N, int K) {
  __shared__ ushort_t Als[128 * 64];
  __shared__ ushort_t Bls[128 * 64];
  const int tid = threadIdx.x;
  const int lane = tid & 63, wave = tid >> 6;
  const int wm = wave >> 1, wn = wave & 1;
  const int q = lane >> 4, l16 = lane & 15;
  const int m0 = blockIdx.y * 128, n0 = blockIdx.x * 128;

  f32x4 acc[4][4];
#pragma unroll
  for (int i = 0; i < 4; i++)
#pragma unroll
    for (int j = 0; j < 4; j++) acc[i][j] = (f32x4){0.f, 0.f, 0.f, 0.f};

  for (int kk = 0; kk < K; kk += 64) {
#pragma unroll
    for (int j = 0; j < 4; j++) {
      int c = j * 256 + tid;
      int r = c >> 3, bl = c & 7, bg = bl ^ (r & 7);
      *(uint4*)&Als[r * 64 + bl * 8] =
          *(const uint4*)&A[(size_t)(m0 + r) * K + kk + bg * 8];
      *(uint4*)&Bls[r * 64 + bl * 8] =
          *(const uint4*)&BT[(size_t)(n0 + r) * K + kk + bg * 8];
    }
    __syncthreads();
#pragma unroll
    for (int c = 0; c < 2; c++) {
      bf16x8 af[4], bf[4];
#pragma unroll
      for (int mt = 0; mt < 4; mt++) {
        int r = wm * 64 + mt * 16 + l16;
        af[mt] = *(const bf16x8*)&Als[r * 64 + (((c * 4 + q) ^ (r & 7)) * 8)];
      }
#pragma unroll
      for (int nt = 0; nt < 4; nt++) {
        int r = wn * 64 + nt * 16 + l16;
        bf[nt] = *(const bf16x8*)&Bls[r * 64 + (((c * 4 + q) ^ (r & 7)) * 8)];
      }
#pragma unroll
      for (int mt = 0; mt < 4; mt++)
#pragma unroll
        for (int nt = 0; nt < 4; nt++)
          acc[mt][nt] = __builtin_amdgcn_mfma_f32_16x16x32_bf16(
              af[mt], bf[nt], acc[mt][nt], 0, 0, 0);
    }
    __syncthreads();
  }
  float dsum = 0.f;
#pragma unroll
  for (int mt = 0; mt < 4; mt++)
#pragma unroll
    for (int nt = 0; nt < 4; nt++) {
      const int gn = n0 + wn * 64 + nt * 16 + l16;
      const int gmb = m0 + wm * 64 + mt * 16 + q * 4;
      const float bvv = biasv[gn];
#pragma unroll
      for (int rg = 0; rg < 4; rg++) {
        const size_t idx = (size_t)(gmb + rg) * N + gn;
        float z = acc[mt][nt][rg] + bvv;
        if constexpr (OUTF32) Cf[idx] = z; else Cb[idx] = f2b(z);
        if constexpr (VDOT)
          if (n0 < 256) dsum += z * vdata[(size_t)(gmb + rg) * 256 + gn];
      }
    }
  if constexpr (VDOT) {
    if (n0 < 256) {
      float s = wave_reduce(dsum);
      if ((tid & 63) == 0) atomicAdd(dacc, (double)(-s));  // cost1 -= v.bv_t
    }
  }
}

// ---------------- chunked RNN scan v5 (R10-proven) ----------------
// 1024 threads, 4-way dot split (w[64]/thread: genuinely register-resident),
// quarters padded to stride 68 (disjoint banks), 32-row Apre staging, warmup 16
// (||Wuu||_2 ~ 0.32 -> 0.32^16 ~ 1e-8, below bf16 rounding).
__global__ __launch_bounds__(1024, 1)
void rnn_scan(const float* __restrict__ Apre, const float* __restrict__ Wuu,
              ushort_t* __restrict__ shifted) {
  const int tid = threadIdx.x;
  const int j = tid >> 2;
  const int s = tid & 3;
  const int t_begin = blockIdx.x * 128;
  const int t_end = t_begin + 128;
  const int t0 = (t_begin >= 16) ? (t_begin - 16) : 0;

  float w[64];
#pragma unroll
  for (int i = 0; i < 64; i++) w[i] = Wuu[(size_t)(s * 64 + i) * 256 + j];

  __shared__ float u[2][280];
  __shared__ float asg[32 * 256];
  if (tid < 256) u[0][(tid >> 6) * 68 + (tid & 63)] = 0.f;
  if (blockIdx.x == 0 && s == 0) shifted[j] = 0;
  __syncthreads();

  const int jp = (j >> 6) * 68 + (j & 63);
  int p = 0;
  for (int tb = t0; tb < t_end; tb += 32) {
    int srow = tb + (tid >> 5);
    if (srow >= S_LEN) srow = S_LEN - 1;
    int scol = (tid & 31) * 8;
    float4 a0 = *(const float4*)&Apre[(size_t)srow * 256 + scol];
    float4 a1 = *(const float4*)&Apre[(size_t)srow * 256 + scol + 4];
    *(float4*)&asg[(tid >> 5) * 256 + scol] = a0;
    *(float4*)&asg[(tid >> 5) * 256 + scol + 4] = a1;
    __syncthreads();
#pragma unroll 1
    for (int i = 0; i < 32; i++) {
      const int t = tb + i;
      if (t >= t_end) break;
      float p0 = 0.f, p1 = 0.f, p2 = 0.f, p3 = 0.f;
#pragma unroll
      for (int qq = 0; qq < 64; qq += 4) {
        float4 uv = *(const float4*)&u[p][s * 68 + qq];
        p0 = fmaf(uv.x, w[qq + 0], p0);
        p1 = fmaf(uv.y, w[qq + 1], p1);
        p2 = fmaf(uv.z, w[qq + 2], p2);
        p3 = fmaf(uv.w, w[qq + 3], p3);
      }
      float ps = (p0 + p1) + (p2 + p3);
      ps += __shfl_xor(ps, 1, 64);
      ps += __shfl_xor(ps, 2, 64);
      float z = asg[i * 256 + j] + ps;
      float e = __expf(2.f * z);
      float unew = 1.f - 2.f * __builtin_amdgcn_rcpf(e + 1.f);
      if (s == 0) {
        u[1 - p][jp] = unew;
        if (t >= t_begin && (t + 1) < S_LEN)
          shifted[(size_t)(t + 1) * 256 + j] = f2b(unew);
      }
      __syncthreads();
      p ^= 1;
    }
  }
}

// ---------------- single prep kernel ----------------
__global__ __launch_bounds__(256)
void prep_all(const float* __restrict__ v_seq, ushort_t* __restrict__ vseq_bf,
              const float* __restrict__ Wyv, const float* __restrict__ Wyh1,
              const float* __restrict__ Wyh2, ushort_t* __restrict__ Wycat,
              const float* __restrict__ W1, ushort_t* __restrict__ BTw1t,
              ushort_t* __restrict__ BTw1,
              const float* __restrict__ W2, ushort_t* __restrict__ BTw2t,
              ushort_t* __restrict__ BTw2,
              const float* __restrict__ Wvu, ushort_t* __restrict__ BTwvu,
              const float* __restrict__ bv, const float* __restrict__ bh1,
              const float* __restrict__ bh2, float* __restrict__ bveccat) {
  int b = blockIdx.x;
  const int tid = threadIdx.x;
  if (b < 32768) { int i = b * 256 + tid; vseq_bf[i] = f2b(v_seq[i]); return; }
  b -= 32768;
  if (b < 256)  { int i = b * 256 + tid; Wycat[i] = f2b(Wyv[i]); return; }
  b -= 256;
  if (b < 512)  { int i = b * 256 + tid; Wycat[65536 + i] = f2b(Wyh1[i]); return; }
  b -= 512;
  if (b < 512)  { int i = b * 256 + tid; Wycat[196608 + i] = f2b(Wyh2[i]); return; }
  b -= 512;
  if (b < 512)  { int i = b * 256 + tid; BTw1t[i] = f2b(W1[i]); return; }
  b -= 512;
  if (b < 1024) { int i = b * 256 + tid; BTw2t[i] = f2b(W2[i]); return; }
  b -= 1024;
  if (b < 256)  { int i = b * 256 + tid; int r = i >> 8, c = i & 255;
                  BTwvu[c * 256 + r] = f2b(Wvu[i]); return; }
  b -= 256;
  if (b < 512)  { int i = b * 256 + tid; int r = i >> 9, c = i & 511;
                  BTw1[(size_t)c * 256 + r] = f2b(W1[i]); return; }
  b -= 512;
  if (b < 1024) { int i = b * 256 + tid; int r = i >> 9, c = i & 511;
                  BTw2[(size_t)c * 512 + r] = f2b(W2[i]); return; }
  b -= 1024;
  { int i = b * 256 + tid;
    if (i < 1280)
      bveccat[i] = (i < 256) ? bv[i] : (i < 768) ? bh1[i - 256] : bh2[i - 768]; }
}

__global__ void finalize_kernel(const double* __restrict__ acc, float* __restrict__ out) {
  out[0] = (float)(acc[0] / (double)S_LEN);
  out[1] = (float)(acc[1] / (double)S_LEN);
}

// ---------------- host orchestration ----------------
extern "C" void kernel_launch(void* const* d_in, const int* in_sizes, int n_in,
                              void* d_out, int out_size, void* d_ws, size_t ws_size,
                              hipStream_t stream) {
  (void)in_sizes; (void)n_in; (void)out_size; (void)ws_size;
  const float* v_seq = (const float*)d_in[0];
  const float* W1    = (const float*)d_in[1];
  const float* bv    = (const float*)d_in[2];
  const float* bh1   = (const float*)d_in[3];
  const float* W2    = (const float*)d_in[4];
  const float* bh2   = (const float*)d_in[5];
  const float* Wyv   = (const float*)d_in[6];
  const float* Wyh1  = (const float*)d_in[7];
  const float* Wyh2  = (const float*)d_in[8];
  const float* Wvu   = (const float*)d_in[9];
  const float* Wuu   = (const float*)d_in[10];
  const float* bu    = (const float*)d_in[11];
  float* out = (float*)d_out;

  const size_t SN = (size_t)S_LEN * NV;   // 8.4M
  const size_t SH = (size_t)S_LEN * NH;   // 16.8M
  const int NB = NV + NH + NH;            // 1280
  char* base = (char*)d_ws;
  size_t cur = 0;
  auto take = [&](size_t bytes) { size_t o = cur; cur += (bytes + 255) & ~(size_t)255; return o; };
  double*   acc      = (double*)  (base + take(64));
  ushort_t* BTwvu    = (ushort_t*)(base + take(65536 * 2));
  ushort_t* Wycat    = (ushort_t*)(base + take((size_t)NB * NR * 2));
  float*    bveccat  = (float*)   (base + take(NB * 4));
  ushort_t* BTw1     = (ushort_t*)(base + take(131072 * 2));   // W1^T [512,256]
  ushort_t* BTw1t    = (ushort_t*)(base + take(131072 * 2));   // W1   [256,512]
  ushort_t* BTw2     = (ushort_t*)(base + take(262144 * 2));   // W2^T [512,512]
  ushort_t* BTw2t    = (ushort_t*)(base + take(262144 * 2));   // W2   [512,512]
  ushort_t* vseq_bf  = (ushort_t*)(base + take(SN * 2));       // + shifted = sampC span
  ushort_t* shifted  = (ushort_t*)(base + take(SN * 2));
  ushort_t* bias_cat = (ushort_t*)(base + take((size_t)S_LEN * NB * 2)); // [S,1280]
  ushort_t* h1buf    = (ushort_t*)(base + take(SH * 2));       // aliased by sampD late
  ushort_t* sampA    = (ushort_t*)(base + take(SH * 2));       // RBM1 h samples
  ushort_t* sampB    = (ushort_t*)(base + take(SN * 2));       // RBM1 v samples
  // Aliases (lifetime-checked):
  float*    Arnn  = (float*)bias_cat;  // consumed by rnn before bias GEMM
  ushort_t* sampC = vseq_bf;           // [S,512] over vseq_bf+shifted; dead after G1
  ushort_t* sampD = h1buf;             // h1buf dead after A0 (dot folded into G1)

  uint32_t ka[20], kb[20];
  uint32_t K0 = 0u, K1 = 42u;
  for (int it = 0; it < 10; it++) {
    uint32_t n0, n1, a0, a1, b0, b1;
    tf2x32(K0, K1, 0u, 0u, &n0, &n1);
    tf2x32(K0, K1, 0u, 1u, &a0, &a1);
    tf2x32(K0, K1, 0u, 2u, &b0, &b1);
    ka[2 * it] = a0; kb[2 * it] = a1;
    ka[2 * it + 1] = b0; kb[2 * it + 1] = b1;
    K0 = n0; K1 = n1;
  }

  hipMemsetAsync(acc, 0, 2 * sizeof(double), stream);

  dim3 blk(256);
  prep_all<<<dim3(37381), blk, 0, stream>>>(
      v_seq, vseq_bf, Wyv, Wyh1, Wyh2, Wycat, W1, BTw1t, BTw1,
      W2, BTw2t, BTw2, Wvu, BTwvu, bv, bh1, bh2, bveccat);

  const int M = S_LEN;
  // 1) Arnn = v_seq @ Wvu + bu (f32)
  gemm_bias<true, false><<<dim3(2, M / 128), blk, 0, stream>>>(
      vseq_bf, BTwvu, bu, nullptr, Arnn, nullptr, nullptr, M, NV, NV);
  // 2) scan -> shifted
  rnn_scan<<<dim3(S_LEN / 128), dim3(1024), 0, stream>>>(Arnn, Wuu, shifted);
  // 3) bias_cat = shifted @ Wycat^T + bveccat; fused v_seq.bv_t data dot
  gemm_bias<false, true><<<dim3(NB / 128, M / 128), blk, 0, stream>>>(
      shifted, Wycat, bveccat, bias_cat, nullptr, v_seq, acc, M, NB, NR);

  const int OFF_BV = 0, OFF_BH1 = NV, OFF_BH2 = NV + NH;
  auto mk = [&](const ushort_t* A, const ushort_t* BT, int boff, ushort_t* C,
                ushort_t* C2, const float* vs, float sign, int key, int N, int K) {
    GemmArgs g;
    g.A = A; g.BT = BT; g.boff = boff; g.C = C; g.C2 = C2; g.vseqf = vs;
    g.fe_acc = acc; g.mon_acc = acc + 1; g.sign = sign;
    g.rk0 = key >= 0 ? ka[key] : 0; g.rk1 = key >= 0 ? kb[key] : 0;
    g.N = N; g.K = K; g.nbx = N / 128;
    return g;
  };

  // G1: sample h (sampA), h1 (h1buf), cost1 -= softplus(z), cost2 -= h1.bh1t
  gemm_samp<F_SAMP | F_H1 | F_FE | F_DOTB><<<dim3(4, M / 128), blk, 0, stream>>>(
      mk(vseq_bf, BTw1, OFF_BH1, sampA, h1buf, nullptr, 1.0f, 0, NH, NV),
      bias_cat, NB);

  // 10 paired dispatches: RBM1 chain (z=0) + RBM2 chain (z=1)
  dim3 pg(4, M / 128, 2);
  GemmArgs V[5], Hh[4], A2g[5], B2g[5];
  for (int it = 0; it < 5; it++) {
    if (it > 0)
      Hh[it - 1] = mk(sampB, BTw1, OFF_BH1, sampA, nullptr, nullptr, 0.f,
                      2 * it, NH, NV);
    V[it] = mk(sampA, BTw1t, OFF_BV, sampB, nullptr,
               (it == 4) ? v_seq : nullptr, (it == 4) ? -1.0f : 0.f,
               2 * it + 1, NV, NH);
    A2g[it] = mk((it == 0) ? h1buf : sampD, BTw2, OFF_BH2, sampC, nullptr, nullptr,
                 (it == 0) ? 1.0f : 0.f, 10 + 2 * it, NH, NH);
    B2g[it] = mk(sampC, BTw2t, OFF_BH1, sampD, nullptr, nullptr,
                 (it == 4) ? -1.0f : 0.f, 11 + 2 * it, NH, NH);
  }
  GemmArgs FE1 = mk(sampB, BTw1, OFF_BH1, nullptr, nullptr, nullptr, -1.0f,
                    -1, NH, NV);
  GemmArgs FE2 = mk(sampD, BTw2, OFF_BH2, nullptr, nullptr, nullptr, -1.0f,
                    -1, NH, NH);

  gemm_pair<F_SAMP, F_SAMP | F_FE><<<pg, blk, 0, stream>>>(V[0], A2g[0], bias_cat, NB);
  gemm_pair<F_SAMP, F_SAMP><<<pg, blk, 0, stream>>>(Hh[0], B2g[0], bias_cat, NB);
  gemm_pair<F_SAMP, F_SAMP><<<pg, blk, 0, stream>>>(V[1], A2g[1], bias_cat, NB);
  gemm_pair<F_SAMP, F_SAMP><<<pg, blk, 0, stream>>>(Hh[1], B2g[1], bias_cat, NB);
  gemm_pair<F_SAMP, F_SAMP><<<pg, blk, 0, stream>>>(V[2], A2g[2], bias_cat, NB);
  gemm_pair<F_SAMP, F_SAMP><<<pg, blk, 0, stream>>>(Hh[2], B2g[2], bias_cat, NB);
  gemm_pair<F_SAMP, F_SAMP><<<pg, blk, 0, stream>>>(V[3], A2g[3], bias_cat, NB);
  gemm_pair<F_SAMP, F_SAMP><<<pg, blk, 0, stream>>>(Hh[3], B2g[3], bias_cat, NB);
  gemm_pair<F_SAMP | F_MON | F_DOTS, F_SAMP><<<pg, blk, 0, stream>>>(
      V[4], A2g[4], bias_cat, NB);
  gemm_pair<F_FE, F_SAMP | F_DOTS><<<pg, blk, 0, stream>>>(FE1, B2g[4], bias_cat, NB);

  // FE2(sample): cost2 += softplus(h1s@W2 + bh2t)
  gemm_samp<F_FE><<<dim3(4, M / 128), blk, 0, stream>>>(FE2, bias_cat, NB);

  finalize_kernel<<<1, 1, 0, stream>>>(acc, out);
}

// Round 15
// 1383.759 us; speedup vs baseline: 1.3634x; 1.3346x over previous
//
#include <hip/hip_runtime.h>
#include <cstdint>

#define S_LEN 32768
#define NV 256
#define NH 512
#define NR 256

typedef short bf16x8 __attribute__((ext_vector_type(8)));
typedef float f32x4 __attribute__((ext_vector_type(4)));
typedef unsigned short ushort_t;
typedef ushort_t u16x8 __attribute__((ext_vector_type(8)));

// ---------------- bf16 helpers (bit-level, RTNE) ----------------
__device__ __forceinline__ float b2f(ushort_t u) {
  return __uint_as_float(((uint32_t)u) << 16);
}
__device__ __forceinline__ ushort_t f2b(float f) {
  uint32_t x = __float_as_uint(f);
  uint32_t r = (x + 0x7fffu + ((x >> 16) & 1u)) >> 16;
  return (ushort_t)r;
}

// ---------------- host threefry2x32 (key-chain derivation) ----------------
#define TFR(x0,x1,r) { x0 += x1; x1 = ((x1 << (r)) | (x1 >> (32 - (r)))); x1 ^= x0; }
__host__ __forceinline__ void tf2x32(uint32_t k0, uint32_t k1,
                                     uint32_t x0, uint32_t x1,
                                     uint32_t* o0, uint32_t* o1) {
  uint32_t k2 = k0 ^ k1 ^ 0x1BD11BDAu;
  x0 += k0; x1 += k1;
  TFR(x0,x1,13) TFR(x0,x1,15) TFR(x0,x1,26) TFR(x0,x1,6)
  x0 += k1; x1 += k2 + 1u;
  TFR(x0,x1,17) TFR(x0,x1,29) TFR(x0,x1,16) TFR(x0,x1,24)
  x0 += k2; x1 += k0 + 2u;
  TFR(x0,x1,13) TFR(x0,x1,15) TFR(x0,x1,26) TFR(x0,x1,6)
  x0 += k0; x1 += k1 + 3u;
  TFR(x0,x1,17) TFR(x0,x1,29) TFR(x0,x1,16) TFR(x0,x1,24)
  x0 += k1; x1 += k2 + 4u;
  TFR(x0,x1,13) TFR(x0,x1,15) TFR(x0,x1,26) TFR(x0,x1,6)
  x0 += k2; x1 += k0 + 5u;
  *o0 = x0; *o1 = x1;
}

// ---------------- device RNG: murmur3 full-avalanche counter hash ----------------
__device__ __forceinline__ float fast_uniform(uint32_t k0, uint32_t k1, uint32_t idx) {
  uint32_t h = idx ^ k0;
  h *= 0xCC9E2D51u; h = (h << 15) | (h >> 17); h *= 0x1B873593u;
  h ^= k1;
  h ^= h >> 16; h *= 0x85EBCA6Bu;
  h ^= h >> 13; h *= 0xC2B2AE35u;
  h ^= h >> 16;
  return __uint_as_float((h >> 9) | 0x3f800000u) - 1.0f;
}

__device__ __forceinline__ float wave_reduce(float v) {
#pragma unroll
  for (int o = 32; o > 0; o >>= 1) v += __shfl_down(v, o, 64);
  return v;
}
__device__ __forceinline__ float softplusf(float z) {
  return fmaxf(z, 0.f) + log1pf(expf(-fabsf(z)));
}

// ---------------- epilogue flags ----------------
#define F_SAMP  4    // Bernoulli sample -> C (u8 0/1)
#define F_H1    8    // sigmoid -> C2 (bf16)
#define F_FE    16   // softplus sum -> fe_acc (acc += -sign*sum)
#define F_MON   32   // monitor sum vs vseqf -> mon_acc
#define F_DOTB  64   // fe_sum += p * bias_elem   (h1 . bh1t, folded into G1)
#define F_DOTS  128  // fe_sum += sample * bias_elem (sample-side dots)

struct GemmArgs {
  const ushort_t* A;   // [M,K] bf16, or u8 when the dispatch's AU8=true
  const ushort_t* BT;  // [N,K] bf16
  int boff;            // bias_cat column offset
  ushort_t* C;         // sample out [M,N] (stored as u8)
  ushort_t* C2;        // sigmoid out (F_H1, bf16)
  const float* vseqf;  // f32 v_seq for F_MON
  double* fe_acc;
  double* mon_acc;
  float sign;
  uint32_t rk0, rk1;
  int N, K, nbx;       // nbx = N/128 (x-block guard for paired launches)
};

// ---------------- core GEMM body — R10 champion config + u8 sample A/C ----------
// R14 vs R10 proved chip-state noise (~28%: identical code+counters, 160 vs 262us/
// pair) — so optimize the reproducible signal: bytes moved. Samples are exactly
// {0,1}: store u8 (halves sample WRITE and sample-A FETCH). Staging expands
// u8 -> bf16 in-register (byte ? 0x3f80 : 0) -> MFMA inputs bit-identical.
// Everything else R10-verbatim (all other perturbations R11/R12/R13 regressed).
template<int FLAGS, bool AU8>
__device__ __forceinline__ void run_gemm(const GemmArgs& g,
                                         const ushort_t* __restrict__ biasm, int ldb,
                                         ushort_t* __restrict__ Als,
                                         ushort_t* __restrict__ Bls) {
  const int tid = threadIdx.x;
  const int lane = tid & 63, wave = tid >> 6;
  const int wm = wave >> 1, wn = wave & 1;
  const int q = lane >> 4, l16 = lane & 15;
  const int m0 = blockIdx.y * 128, n0 = blockIdx.x * 128;
  const int N = g.N, K = g.K;

  f32x4 acc[4][4];
#pragma unroll
  for (int mt = 0; mt < 4; mt++)
#pragma unroll
    for (int nt = 0; nt < 4; nt++) {
      const int gn = n0 + wn * 64 + nt * 16 + l16;
      const int gmb = m0 + wm * 64 + mt * 16 + q * 4;
#pragma unroll
      for (int rg = 0; rg < 4; rg++)
        acc[mt][nt][rg] = b2f(biasm[(size_t)(gmb + rg) * ldb + g.boff + gn]);
    }

  for (int kk = 0; kk < K; kk += 64) {
#pragma unroll
    for (int j = 0; j < 4; j++) {
      int c = j * 256 + tid;
      int r = c >> 3, bl = c & 7, bg = bl ^ (r & 7);
      if constexpr (AU8) {
        const uint8_t* A8 = (const uint8_t*)g.A;
        uint2 v8 = *(const uint2*)&A8[(size_t)(m0 + r) * K + kk + bg * 8];
        u16x8 ex;
#pragma unroll
        for (int i = 0; i < 4; i++) {
          ex[i]     = ((v8.x >> (8 * i)) & 0xffu) ? (ushort_t)0x3f80 : (ushort_t)0;
          ex[4 + i] = ((v8.y >> (8 * i)) & 0xffu) ? (ushort_t)0x3f80 : (ushort_t)0;
        }
        *(u16x8*)&Als[r * 64 + bl * 8] = ex;
      } else {
        *(uint4*)&Als[r * 64 + bl * 8] =
            *(const uint4*)&g.A[(size_t)(m0 + r) * K + kk + bg * 8];
      }
      *(uint4*)&Bls[r * 64 + bl * 8] =
          *(const uint4*)&g.BT[(size_t)(n0 + r) * K + kk + bg * 8];
    }
    __syncthreads();
#pragma unroll
    for (int c = 0; c < 2; c++) {
      bf16x8 af[4], bf[4];
#pragma unroll
      for (int mt = 0; mt < 4; mt++) {
        int r = wm * 64 + mt * 16 + l16;
        af[mt] = *(const bf16x8*)&Als[r * 64 + (((c * 4 + q) ^ (r & 7)) * 8)];
      }
#pragma unroll
      for (int nt = 0; nt < 4; nt++) {
        int r = wn * 64 + nt * 16 + l16;
        bf[nt] = *(const bf16x8*)&Bls[r * 64 + (((c * 4 + q) ^ (r & 7)) * 8)];
      }
#pragma unroll
      for (int mt = 0; mt < 4; mt++)
#pragma unroll
        for (int nt = 0; nt < 4; nt++)
          acc[mt][nt] = __builtin_amdgcn_mfma_f32_16x16x32_bf16(
              af[mt], bf[nt], acc[mt][nt], 0, 0, 0);
    }
    __syncthreads();
  }

  float fe_sum = 0.f, mon_sum = 0.f;
#pragma unroll
  for (int mt = 0; mt < 4; mt++) {
#pragma unroll
    for (int nt = 0; nt < 4; nt++) {
      const int gn = n0 + wn * 64 + nt * 16 + l16;
      const int gmb = m0 + wm * 64 + mt * 16 + q * 4;
#pragma unroll
      for (int rg = 0; rg < 4; rg++) {
        const int gm = gmb + rg;
        const size_t idx = (size_t)gm * N + gn;
        float z = acc[mt][nt][rg];  // bias already inside
        float be = 0.f;
        if constexpr (FLAGS & (F_DOTB | F_DOTS))
          be = b2f(biasm[(size_t)gm * ldb + g.boff + gn]);
        if constexpr (FLAGS & (F_SAMP | F_H1 | F_MON)) {
          float e = __expf(-z);
          if constexpr (FLAGS & F_SAMP) {
            float uu = fast_uniform(g.rk0, g.rk1, (uint32_t)idx);
            bool sbit = fmaf(uu, e, uu) < 1.f;  // u < sigmoid(z)
            ((uint8_t*)g.C)[idx] = sbit ? (uint8_t)1 : (uint8_t)0;
            if constexpr (FLAGS & F_DOTS) fe_sum += sbit ? be : 0.f;
          }
          if constexpr (FLAGS & (F_H1 | F_MON)) {
            float pp = __builtin_amdgcn_rcpf(1.f + e);
            if constexpr (FLAGS & F_H1) g.C2[idx] = f2b(pp);
            if constexpr (FLAGS & F_DOTB) fe_sum += pp * be;
            if constexpr (FLAGS & F_MON) {
              float v = g.vseqf[idx];
              mon_sum += (v != 0.f) ? logf(pp + 1e-10f) : logf(1.f - pp + 1e-10f);
            }
          }
        }
        if constexpr (FLAGS & F_FE) fe_sum += softplusf(z);
      }
    }
  }
  if constexpr (FLAGS & (F_FE | F_DOTB | F_DOTS)) {
    float s = wave_reduce(fe_sum);
    if (lane == 0) atomicAdd(g.fe_acc, (double)(-g.sign * s));
  }
  if constexpr (FLAGS & F_MON) {
    float s = wave_reduce(mon_sum);
    if (lane == 0) atomicAdd(g.mon_acc, (double)s);
  }
}

template<int FLAGS, bool AU8>
__global__ __launch_bounds__(256)
void gemm_samp(GemmArgs g, const ushort_t* __restrict__ biasm, int ldb) {
  __shared__ ushort_t Als[128 * 64];
  __shared__ ushort_t Bls[128 * 64];
  if ((int)blockIdx.x >= g.nbx) return;
  run_gemm<FLAGS, AU8>(g, biasm, ldb, Als, Bls);
}

// Paired launch: z=0 runs g0 (RBM1 step), z=1 runs g1 (RBM2 step) — independent.
template<int F0, bool U0, int F1, bool U1>
__global__ __launch_bounds__(256)
void gemm_pair(GemmArgs g0, GemmArgs g1, const ushort_t* __restrict__ biasm, int ldb) {
  __shared__ ushort_t Als[128 * 64];
  __shared__ ushort_t Bls[128 * 64];
  if (blockIdx.z == 0) {
    if ((int)blockIdx.x >= g0.nbx) return;
    run_gemm<F0, U0>(g0, biasm, ldb, Als, Bls);
  } else {
    if ((int)blockIdx.x >= g1.nbx) return;
    run_gemm<F1, U1>(g1, biasm, ldb, Als, Bls);
  }
}

// ---------------- plain GEMM + f32-vector bias (Arnn / bias_cat) --------------------
// VDOT (bias_cat GEMM only): for n0<256 accumulate z * v_seq[gm,gn] -> acc += -sum
template<bool OUTF32, bool VDOT>
__global__ __launch_bounds__(256)
void gemm_bias(const ushort_t* __restrict__ A, const ushort_t* __restrict__ BT,
               const float* __restrict__ biasv, ushort_t* __restrict__ Cb,
               float* __restrict__ Cf, const float* __restrict__ vdata,
               double* __restrict__ dacc, int M, int N, int K) {
  __shared__ ushort_t Als[128 * 64];
  __shared__ ushort_t Bls[128 * 64];
  const int tid = threadIdx.x;
  const int lane = tid & 63, wave = tid >> 6;
  const int wm = wave >> 1, wn = wave & 1;
  const int q = lane >> 4, l16 = lane & 15;
  const int m0 = blockIdx.y * 128, n0 = blockIdx.x * 128;

  f32x4 acc[4][4];
#pragma unroll
  for (int i = 0; i < 4; i++)
#pragma unroll
    for (int j = 0; j < 4; j++) acc[i][j] = (f32x4){0.f, 0.f, 0.f, 0.f};

  for (int kk = 0; kk < K; kk += 64) {
#pragma unroll
    for (int j = 0; j < 4; j++) {
      int c = j * 256 + tid;
      int r = c >> 3, bl = c & 7, bg = bl ^ (r & 7);
      *(uint4*)&Als[r * 64 + bl * 8] =
          *(const uint4*)&A[(size_t)(m0 + r) * K + kk + bg * 8];
      *(uint4*)&Bls[r * 64 + bl * 8] =
          *(const uint4*)&BT[(size_t)(n0 + r) * K + kk + bg * 8];
    }
    __syncthreads();
#pragma unroll
    for (int c = 0; c < 2; c++) {
      bf16x8 af[4], bf[4];
#pragma unroll
      for (int mt = 0; mt < 4; mt++) {
        int r = wm * 64 + mt * 16 + l16;
        af[mt] = *(const bf16x8*)&Als[r * 64 + (((c * 4 + q) ^ (r & 7)) * 8)];
      }
#pragma unroll
      for (int nt = 0; nt < 4; nt++) {
        int r = wn * 64 + nt * 16 + l16;
        bf[nt] = *(const bf16x8*)&Bls[r * 64 + (((c * 4 + q) ^ (r & 7)) * 8)];
      }
#pragma unroll
      for (int mt = 0; mt < 4; mt++)
#pragma unroll
        for (int nt = 0; nt < 4; nt++)
          acc[mt][nt] = __builtin_amdgcn_mfma_f32_16x16x32_bf16(
              af[mt], bf[nt], acc[mt][nt], 0, 0, 0);
    }
    __syncthreads();
  }
  float dsum = 0.f;
#pragma unroll
  for (int mt = 0; mt < 4; mt++)
#pragma unroll
    for (int nt = 0; nt < 4; nt++) {
      const int gn = n0 + wn * 64 + nt * 16 + l16;
      const int gmb = m0 + wm * 64 + mt * 16 + q * 4;
      const float bvv = biasv[gn];
#pragma unroll
      for (int rg = 0; rg < 4; rg++) {
        const size_t idx = (size_t)(gmb + rg) * N + gn;
        float z = acc[mt][nt][rg] + bvv;
        if constexpr (OUTF32) Cf[idx] = z; else Cb[idx] = f2b(z);
        if constexpr (VDOT)
          if (n0 < 256) dsum += z * vdata[(size_t)(gmb + rg) * 256 + gn];
      }
    }
  if constexpr (VDOT) {
    if (n0 < 256) {
      float s = wave_reduce(dsum);
      if ((tid & 63) == 0) atomicAdd(dacc, (double)(-s));  // cost1 -= v.bv_t
    }
  }
}

// ---------------- chunked RNN scan v5 (R10-proven) ----------------
__global__ __launch_bounds__(1024, 1)
void rnn_scan(const float* __restrict__ Apre, const float* __restrict__ Wuu,
              ushort_t* __restrict__ shifted) {
  const int tid = threadIdx.x;
  const int j = tid >> 2;
  const int s = tid & 3;
  const int t_begin = blockIdx.x * 128;
  const int t_end = t_begin + 128;
  const int t0 = (t_begin >= 16) ? (t_begin - 16) : 0;

  float w[64];
#pragma unroll
  for (int i = 0; i < 64; i++) w[i] = Wuu[(size_t)(s * 64 + i) * 256 + j];

  __shared__ float u[2][280];
  __shared__ float asg[32 * 256];
  if (tid < 256) u[0][(tid >> 6) * 68 + (tid & 63)] = 0.f;
  if (blockIdx.x == 0 && s == 0) shifted[j] = 0;
  __syncthreads();

  const int jp = (j >> 6) * 68 + (j & 63);
  int p = 0;
  for (int tb = t0; tb < t_end; tb += 32) {
    int srow = tb + (tid >> 5);
    if (srow >= S_LEN) srow = S_LEN - 1;
    int scol = (tid & 31) * 8;
    float4 a0 = *(const float4*)&Apre[(size_t)srow * 256 + scol];
    float4 a1 = *(const float4*)&Apre[(size_t)srow * 256 + scol + 4];
    *(float4*)&asg[(tid >> 5) * 256 + scol] = a0;
    *(float4*)&asg[(tid >> 5) * 256 + scol + 4] = a1;
    __syncthreads();
#pragma unroll 1
    for (int i = 0; i < 32; i++) {
      const int t = tb + i;
      if (t >= t_end) break;
      float p0 = 0.f, p1 = 0.f, p2 = 0.f, p3 = 0.f;
#pragma unroll
      for (int qq = 0; qq < 64; qq += 4) {
        float4 uv = *(const float4*)&u[p][s * 68 + qq];
        p0 = fmaf(uv.x, w[qq + 0], p0);
        p1 = fmaf(uv.y, w[qq + 1], p1);
        p2 = fmaf(uv.z, w[qq + 2], p2);
        p3 = fmaf(uv.w, w[qq + 3], p3);
      }
      float ps = (p0 + p1) + (p2 + p3);
      ps += __shfl_xor(ps, 1, 64);
      ps += __shfl_xor(ps, 2, 64);
      float z = asg[i * 256 + j] + ps;
      float e = __expf(2.f * z);
      float unew = 1.f - 2.f * __builtin_amdgcn_rcpf(e + 1.f);
      if (s == 0) {
        u[1 - p][jp] = unew;
        if (t >= t_begin && (t + 1) < S_LEN)
          shifted[(size_t)(t + 1) * 256 + j] = f2b(unew);
      }
      __syncthreads();
      p ^= 1;
    }
  }
}

// ---------------- single prep kernel ----------------
__global__ __launch_bounds__(256)
void prep_all(const float* __restrict__ v_seq, ushort_t* __restrict__ vseq_bf,
              const float* __restrict__ Wyv, const float* __restrict__ Wyh1,
              const float* __restrict__ Wyh2, ushort_t* __restrict__ Wycat,
              const float* __restrict__ W1, ushort_t* __restrict__ BTw1t,
              ushort_t* __restrict__ BTw1,
              const float* __restrict__ W2, ushort_t* __restrict__ BTw2t,
              ushort_t* __restrict__ BTw2,
              const float* __restrict__ Wvu, ushort_t* __restrict__ BTwvu,
              const float* __restrict__ bv, const float* __restrict__ bh1,
              const float* __restrict__ bh2, float* __restrict__ bveccat) {
  int b = blockIdx.x;
  const int tid = threadIdx.x;
  if (b < 32768) { int i = b * 256 + tid; vseq_bf[i] = f2b(v_seq[i]); return; }
  b -= 32768;
  if (b < 256)  { int i = b * 256 + tid; Wycat[i] = f2b(Wyv[i]); return; }
  b -= 256;
  if (b < 512)  { int i = b * 256 + tid; Wycat[65536 + i] = f2b(Wyh1[i]); return; }
  b -= 512;
  if (b < 512)  { int i = b * 256 + tid; Wycat[196608 + i] = f2b(Wyh2[i]); return; }
  b -= 512;
  if (b < 512)  { int i = b * 256 + tid; BTw1t[i] = f2b(W1[i]); return; }
  b -= 512;
  if (b < 1024) { int i = b * 256 + tid; BTw2t[i] = f2b(W2[i]); return; }
  b -= 1024;
  if (b < 256)  { int i = b * 256 + tid; int r = i >> 8, c = i & 255;
                  BTwvu[c * 256 + r] = f2b(Wvu[i]); return; }
  b -= 256;
  if (b < 512)  { int i = b * 256 + tid; int r = i >> 9, c = i & 511;
                  BTw1[(size_t)c * 256 + r] = f2b(W1[i]); return; }
  b -= 512;
  if (b < 1024) { int i = b * 256 + tid; int r = i >> 9, c = i & 511;
                  BTw2[(size_t)c * 512 + r] = f2b(W2[i]); return; }
  b -= 1024;
  { int i = b * 256 + tid;
    if (i < 1280)
      bveccat[i] = (i < 256) ? bv[i] : (i < 768) ? bh1[i - 256] : bh2[i - 768]; }
}

__global__ void finalize_kernel(const double* __restrict__ acc, float* __restrict__ out) {
  out[0] = (float)(acc[0] / (double)S_LEN);
  out[1] = (float)(acc[1] / (double)S_LEN);
}

// ---------------- host orchestration ----------------
extern "C" void kernel_launch(void* const* d_in, const int* in_sizes, int n_in,
                              void* d_out, int out_size, void* d_ws, size_t ws_size,
                              hipStream_t stream) {
  (void)in_sizes; (void)n_in; (void)out_size; (void)ws_size;
  const float* v_seq = (const float*)d_in[0];
  const float* W1    = (const float*)d_in[1];
  const float* bv    = (const float*)d_in[2];
  const float* bh1   = (const float*)d_in[3];
  const float* W2    = (const float*)d_in[4];
  const float* bh2   = (const float*)d_in[5];
  const float* Wyv   = (const float*)d_in[6];
  const float* Wyh1  = (const float*)d_in[7];
  const float* Wyh2  = (const float*)d_in[8];
  const float* Wvu   = (const float*)d_in[9];
  const float* Wuu   = (const float*)d_in[10];
  const float* bu    = (const float*)d_in[11];
  float* out = (float*)d_out;

  const size_t SN = (size_t)S_LEN * NV;   // 8.4M
  const size_t SH = (size_t)S_LEN * NH;   // 16.8M
  const int NB = NV + NH + NH;            // 1280
  char* base = (char*)d_ws;
  size_t cur = 0;
  auto take = [&](size_t bytes) { size_t o = cur; cur += (bytes + 255) & ~(size_t)255; return o; };
  double*   acc      = (double*)  (base + take(64));
  ushort_t* BTwvu    = (ushort_t*)(base + take(65536 * 2));
  ushort_t* Wycat    = (ushort_t*)(base + take((size_t)NB * NR * 2));
  float*    bveccat  = (float*)   (base + take(NB * 4));
  ushort_t* BTw1     = (ushort_t*)(base + take(131072 * 2));   // W1^T [512,256]
  ushort_t* BTw1t    = (ushort_t*)(base + take(131072 * 2));   // W1   [256,512]
  ushort_t* BTw2     = (ushort_t*)(base + take(262144 * 2));   // W2^T [512,512]
  ushort_t* BTw2t    = (ushort_t*)(base + take(262144 * 2));   // W2   [512,512]
  ushort_t* vseq_bf  = (ushort_t*)(base + take(SN * 2));
  ushort_t* shifted  = (ushort_t*)(base + take(SN * 2));
  ushort_t* bias_cat = (ushort_t*)(base + take((size_t)S_LEN * NB * 2)); // [S,1280]
  ushort_t* h1buf    = (ushort_t*)(base + take(SH * 2));       // bf16 sigmoid probs
  uint8_t*  sampA8   = (uint8_t*) (base + take(SH));           // RBM1 h samples u8
  uint8_t*  sampB8   = (uint8_t*) (base + take(SN));           // RBM1 v samples u8
  // Aliases (lifetime-checked):
  float*   Arnn   = (float*)bias_cat;   // consumed by rnn before bias GEMM
  uint8_t* sampC8 = (uint8_t*)vseq_bf;  // [S,512] u8 = 16.8MB fits in vseq_bf region;
                                        // vseq_bf (bf16) dead after G1
  uint8_t* sampD8 = (uint8_t*)h1buf;    // h1buf dead after A0 (dot folded into G1)

  uint32_t ka[20], kb[20];
  uint32_t K0 = 0u, K1 = 42u;
  for (int it = 0; it < 10; it++) {
    uint32_t n0, n1, a0, a1, b0, b1;
    tf2x32(K0, K1, 0u, 0u, &n0, &n1);
    tf2x32(K0, K1, 0u, 1u, &a0, &a1);
    tf2x32(K0, K1, 0u, 2u, &b0, &b1);
    ka[2 * it] = a0; kb[2 * it] = a1;
    ka[2 * it + 1] = b0; kb[2 * it + 1] = b1;
    K0 = n0; K1 = n1;
  }

  hipMemsetAsync(acc, 0, 2 * sizeof(double), stream);

  dim3 blk(256);
  prep_all<<<dim3(37381), blk, 0, stream>>>(
      v_seq, vseq_bf, Wyv, Wyh1, Wyh2, Wycat, W1, BTw1t, BTw1,
      W2, BTw2t, BTw2, Wvu, BTwvu, bv, bh1, bh2, bveccat);

  const int M = S_LEN;
  gemm_bias<true, false><<<dim3(2, M / 128), blk, 0, stream>>>(
      vseq_bf, BTwvu, bu, nullptr, Arnn, nullptr, nullptr, M, NV, NV);
  rnn_scan<<<dim3(S_LEN / 128), dim3(1024), 0, stream>>>(Arnn, Wuu, shifted);
  gemm_bias<false, true><<<dim3(NB / 128, M / 128), blk, 0, stream>>>(
      shifted, Wycat, bveccat, bias_cat, nullptr, v_seq, acc, M, NB, NR);

  const int OFF_BV = 0, OFF_BH1 = NV, OFF_BH2 = NV + NH;
  auto mk = [&](const void* A, const ushort_t* BT, int boff, void* C,
                ushort_t* C2, const float* vs, float sign, int key, int N, int K) {
    GemmArgs g;
    g.A = (const ushort_t*)A; g.BT = BT; g.boff = boff;
    g.C = (ushort_t*)C; g.C2 = C2; g.vseqf = vs;
    g.fe_acc = acc; g.mon_acc = acc + 1; g.sign = sign;
    g.rk0 = key >= 0 ? ka[key] : 0; g.rk1 = key >= 0 ? kb[key] : 0;
    g.N = N; g.K = K; g.nbx = N / 128;
    return g;
  };

  // G1: sample h (sampA u8), h1 (h1buf bf16), cost1 -= softplus, cost2 -= h1.bh1t
  gemm_samp<F_SAMP | F_H1 | F_FE | F_DOTB, false>
      <<<dim3(4, M / 128), blk, 0, stream>>>(
      mk(vseq_bf, BTw1, OFF_BH1, sampA8, h1buf, nullptr, 1.0f, 0, NH, NV),
      bias_cat, NB);

  // 10 paired dispatches: RBM1 chain (z=0) + RBM2 chain (z=1)
  dim3 pg(4, M / 128, 2);
  GemmArgs V[5], Hh[4], A2g[5], B2g[5];
  for (int it = 0; it < 5; it++) {
    if (it > 0)
      Hh[it - 1] = mk(sampB8, BTw1, OFF_BH1, sampA8, nullptr, nullptr, 0.f,
                      2 * it, NH, NV);
    V[it] = mk(sampA8, BTw1t, OFF_BV, sampB8, nullptr,
               (it == 4) ? v_seq : nullptr, (it == 4) ? -1.0f : 0.f,
               2 * it + 1, NV, NH);
    A2g[it] = mk((it == 0) ? (const void*)h1buf : (const void*)sampD8,
                 BTw2, OFF_BH2, sampC8, nullptr, nullptr,
                 (it == 0) ? 1.0f : 0.f, 10 + 2 * it, NH, NH);
    B2g[it] = mk(sampC8, BTw2t, OFF_BH1, sampD8, nullptr, nullptr,
                 (it == 4) ? -1.0f : 0.f, 11 + 2 * it, NH, NH);
  }
  GemmArgs FE1 = mk(sampB8, BTw1, OFF_BH1, nullptr, nullptr, nullptr, -1.0f,
                    -1, NH, NV);
  GemmArgs FE2 = mk(sampD8, BTw2, OFF_BH2, nullptr, nullptr, nullptr, -1.0f,
                    -1, NH, NH);

  gemm_pair<F_SAMP, true, F_SAMP | F_FE, false>
      <<<pg, blk, 0, stream>>>(V[0], A2g[0], bias_cat, NB);   // A2g[0]: A=h1buf bf16
  gemm_pair<F_SAMP, true, F_SAMP, true>
      <<<pg, blk, 0, stream>>>(Hh[0], B2g[0], bias_cat, NB);
  gemm_pair<F_SAMP, true, F_SAMP, true>
      <<<pg, blk, 0, stream>>>(V[1], A2g[1], bias_cat, NB);
  gemm_pair<F_SAMP, true, F_SAMP, true>
      <<<pg, blk, 0, stream>>>(Hh[1], B2g[1], bias_cat, NB);
  gemm_pair<F_SAMP, true, F_SAMP, true>
      <<<pg, blk, 0, stream>>>(V[2], A2g[2], bias_cat, NB);
  gemm_pair<F_SAMP, true, F_SAMP, true>
      <<<pg, blk, 0, stream>>>(Hh[2], B2g[2], bias_cat, NB);
  gemm_pair<F_SAMP, true, F_SAMP, true>
      <<<pg, blk, 0, stream>>>(V[3], A2g[3], bias_cat, NB);
  gemm_pair<F_SAMP, true, F_SAMP, true>
      <<<pg, blk, 0, stream>>>(Hh[3], B2g[3], bias_cat, NB);
  gemm_pair<F_SAMP | F_MON | F_DOTS, true, F_SAMP, true>
      <<<pg, blk, 0, stream>>>(V[4], A2g[4], bias_cat, NB);
  gemm_pair<F_FE, true, F_SAMP | F_DOTS, true>
      <<<pg, blk, 0, stream>>>(FE1, B2g[4], bias_cat, NB);

  // FE2(sample): cost2 += softplus(h1s@W2 + bh2t)
  gemm_samp<F_FE, true><<<dim3(4, M / 128), blk, 0, stream>>>(FE2, bias_cat, NB);

  finalize_kernel<<<1, 1, 0, stream>>>(acc, out);
}